// Round 1
// baseline (104.592 us; speedup 1.0000x reference)
//
#include <hip/hip_runtime.h>
#include <hip/hip_bf16.h>

// GCN forward: out = PReLU(adj @ (seq @ W^T) + bias)
// B=256, N=512, IN_FT=OUT_FT=64. Output fp32.
// Strategy: bf16 MFMA (16x16x32), two kernels:
//   A: seq_fts^T = (seq @ W^T)^T stored bf16 [b][o][tok] in d_ws (16 MB)
//   B: out = adj @ seq_fts, adj fp32 streamed straight into A-frags (no LDS,
//      no barriers -- each adj row is owned by exactly one wave).

#define BATCH 256
#define NTOK  512
#define INF   64
#define OUTF  64

typedef __attribute__((ext_vector_type(8))) __bf16 bf16x8;
typedef __attribute__((ext_vector_type(4))) __bf16 bf16x4;
typedef __attribute__((ext_vector_type(4))) float  f32x4;

__device__ __forceinline__ bf16x8 load_cvt8(const float* __restrict__ p) {
    float4 lo = *(const float4*)p;
    float4 hi = *(const float4*)(p + 4);
    bf16x8 r;
    r[0] = (__bf16)lo.x; r[1] = (__bf16)lo.y; r[2] = (__bf16)lo.z; r[3] = (__bf16)lo.w;
    r[4] = (__bf16)hi.x; r[5] = (__bf16)hi.y; r[6] = (__bf16)hi.z; r[7] = (__bf16)hi.w;
    return r;
}

// ---------------- Kernel A: seq_fts^T = (seq @ W^T)^T -> bf16 ----------------
// grid = 2048 (= 256 batches x 8 token-chunks of 64), block = 256 (4 waves).
// Each wave: one 16-token m-tile x all 64 out_ft (4 n-tiles), K = 64 (2 k-steps).
__global__ __launch_bounds__(256) void GCN_fc_kernel(
        const float* __restrict__ seq, const float* __restrict__ W,
        __bf16* __restrict__ sftT) {
    int blk  = blockIdx.x;
    int b    = blk >> 3;
    int m0   = (blk & 7) * 64;
    int tid  = threadIdx.x;
    int wave = tid >> 6;
    int lane = tid & 63;
    int row16 = lane & 15;
    int g     = lane >> 4;          // k-group 0..3
    int mbase = m0 + wave * 16;

    // A-frag: seq[b][mbase+row16][g*8 + j + ks*32]
    const float* sp = seq + ((size_t)b * NTOK + (mbase + row16)) * INF + g * 8;
    // B-frag: W[nt*16+row16][g*8 + j + ks*32]
    const float* wp = W + (size_t)row16 * INF + g * 8;

    f32x4 acc[4] = {};
#pragma unroll
    for (int ks = 0; ks < 2; ++ks) {
        bf16x8 a = load_cvt8(sp + ks * 32);
#pragma unroll
        for (int nt = 0; nt < 4; ++nt) {
            bf16x8 w8 = load_cvt8(wp + (size_t)nt * 16 * INF + ks * 32);
            acc[nt] = __builtin_amdgcn_mfma_f32_16x16x32_bf16(a, w8, acc[nt], 0, 0, 0);
        }
    }
    // C/D: row(tok) = g*4 + j, col(o) = row16. Store transposed: sftT[b][o][tok]
#pragma unroll
    for (int nt = 0; nt < 4; ++nt) {
        int o = nt * 16 + row16;
        bf16x4 v;
        v[0] = (__bf16)acc[nt][0]; v[1] = (__bf16)acc[nt][1];
        v[2] = (__bf16)acc[nt][2]; v[3] = (__bf16)acc[nt][3];
        __bf16* dst = sftT + ((size_t)b * OUTF + o) * NTOK + mbase + g * 4;
        *(bf16x4*)dst = v;   // 8B store, tok base multiple of 4 -> aligned
    }
}

// ---------------- Kernel B: out = PReLU(adj @ seq_fts + bias) ----------------
// grid = 1024 (= 256 batches x 4 row-chunks of 128), block = 256 (4 waves).
// Each wave: 32 adj rows (2 m-tiles) x 64 out_ft (4 n-tiles). K = 512.
// adj fp32 loaded straight to registers (each row owned by one wave -> no LDS).
__global__ __launch_bounds__(256) void GCN_agg_kernel(
        const float* __restrict__ adj, const __bf16* __restrict__ sftT,
        const float* __restrict__ bias, const float* __restrict__ alpha_p,
        float* __restrict__ out) {
    int blk  = blockIdx.x;
    int b    = blk >> 2;
    int m0   = (blk & 3) * 128;
    int tid  = threadIdx.x;
    int wave = tid >> 6;
    int lane = tid & 63;
    int row16 = lane & 15;
    int g     = lane >> 4;
    int wr    = wave * 32;

    // A-frag row pointers: adj[b][m0+wr+mt*16+row16][k], k = kc + g*8 + j
    const float* arow0 = adj + ((size_t)b * NTOK + (m0 + wr + row16)) * NTOK + g * 8;
    const float* arow1 = arow0 + (size_t)16 * NTOK;
    // B-frag: sftT[b][nt*16+row16][kc + g*8 + j]  (16B contiguous per lane)
    const __bf16* brow = sftT + ((size_t)b * OUTF + row16) * NTOK + g * 8;

    f32x4 acc[2][4] = {};
#pragma unroll 4
    for (int kc = 0; kc < NTOK; kc += 32) {
        bf16x8 a0 = load_cvt8(arow0 + kc);
        bf16x8 a1 = load_cvt8(arow1 + kc);
        bf16x8 bb[4];
#pragma unroll
        for (int nt = 0; nt < 4; ++nt)
            bb[nt] = *(const bf16x8*)(brow + (size_t)nt * 16 * NTOK + kc);
#pragma unroll
        for (int nt = 0; nt < 4; ++nt) {
            acc[0][nt] = __builtin_amdgcn_mfma_f32_16x16x32_bf16(a0, bb[nt], acc[0][nt], 0, 0, 0);
            acc[1][nt] = __builtin_amdgcn_mfma_f32_16x16x32_bf16(a1, bb[nt], acc[1][nt], 0, 0, 0);
        }
    }

    const float alpha = alpha_p[0];
#pragma unroll
    for (int mt = 0; mt < 2; ++mt) {
#pragma unroll
        for (int nt = 0; nt < 4; ++nt) {
            int o = nt * 16 + row16;
            float bv = bias[o];
            int m = m0 + wr + mt * 16 + g * 4;   // C/D row = g*4 + j
            float* op = out + ((size_t)b * NTOK + m) * OUTF + o;
#pragma unroll
            for (int j = 0; j < 4; ++j) {
                float v = acc[mt][nt][j] + bv;
                op[(size_t)j * OUTF] = (v >= 0.f) ? v : alpha * v;
            }
        }
    }
}

extern "C" void kernel_launch(void* const* d_in, const int* in_sizes, int n_in,
                              void* d_out, int out_size, void* d_ws, size_t ws_size,
                              hipStream_t stream) {
    const float* seq   = (const float*)d_in[0];
    const float* adj   = (const float*)d_in[1];
    const float* W     = (const float*)d_in[2];
    const float* bias  = (const float*)d_in[3];
    const float* alpha = (const float*)d_in[4];
    float* out = (float*)d_out;
    __bf16* sftT = (__bf16*)d_ws;   // needs 256*64*512*2 = 16 MB of scratch

    GCN_fc_kernel<<<dim3(2048), dim3(256), 0, stream>>>(seq, W, sftT);
    GCN_agg_kernel<<<dim3(1024), dim3(256), 0, stream>>>(adj, sftT, bias, alpha, out);
}

// Round 3
// 98.613 us; speedup vs baseline: 1.0606x; 1.0606x over previous
//
#include <hip/hip_runtime.h>
#include <hip/hip_bf16.h>

// GCN forward: out = PReLU(adj @ (seq @ W^T) + bias)
// B=256, N=512, IN_FT=OUT_FT=64. Output fp32.
// Kernel A: seq_fts^T bf16 [b][o][tok] into d_ws (unchanged from R1, passed).
// Kernel B: adj staged via global_load_lds (VGPR-free MLP), wave-private
//   double-buffered LDS stripes, counted vmcnt(4), XOR-swizzled source+read.

#define BATCH 256
#define NTOK  512
#define INF   64
#define OUTF  64

typedef __attribute__((ext_vector_type(8))) __bf16 bf16x8;
typedef __attribute__((ext_vector_type(4))) __bf16 bf16x4;
typedef __attribute__((ext_vector_type(4))) float  f32x4;

typedef const __attribute__((address_space(1))) char GChar;
typedef __attribute__((address_space(3))) char LChar;

__device__ __forceinline__ bf16x8 load_cvt8(const float* __restrict__ p) {
    float4 lo = *(const float4*)p;
    float4 hi = *(const float4*)(p + 4);
    bf16x8 r;
    r[0] = (__bf16)lo.x; r[1] = (__bf16)lo.y; r[2] = (__bf16)lo.z; r[3] = (__bf16)lo.w;
    r[4] = (__bf16)hi.x; r[5] = (__bf16)hi.y; r[6] = (__bf16)hi.z; r[7] = (__bf16)hi.w;
    return r;
}

__device__ __forceinline__ bf16x8 pack8(float4 lo, float4 hi) {
    bf16x8 r;
    r[0] = (__bf16)lo.x; r[1] = (__bf16)lo.y; r[2] = (__bf16)lo.z; r[3] = (__bf16)lo.w;
    r[4] = (__bf16)hi.x; r[5] = (__bf16)hi.y; r[6] = (__bf16)hi.z; r[7] = (__bf16)hi.w;
    return r;
}

// ---------------- Kernel A: seq_fts^T = (seq @ W^T)^T -> bf16 ----------------
__global__ __launch_bounds__(256) void GCN_fc_kernel(
        const float* __restrict__ seq, const float* __restrict__ W,
        __bf16* __restrict__ sftT) {
    int blk  = blockIdx.x;
    int b    = blk >> 3;
    int m0   = (blk & 7) * 64;
    int tid  = threadIdx.x;
    int wave = tid >> 6;
    int lane = tid & 63;
    int row16 = lane & 15;
    int g     = lane >> 4;
    int mbase = m0 + wave * 16;

    const float* sp = seq + ((size_t)b * NTOK + (mbase + row16)) * INF + g * 8;
    const float* wp = W + (size_t)row16 * INF + g * 8;

    f32x4 acc[4] = {};
#pragma unroll
    for (int ks = 0; ks < 2; ++ks) {
        bf16x8 a = load_cvt8(sp + ks * 32);
#pragma unroll
        for (int nt = 0; nt < 4; ++nt) {
            bf16x8 w8 = load_cvt8(wp + (size_t)nt * 16 * INF + ks * 32);
            acc[nt] = __builtin_amdgcn_mfma_f32_16x16x32_bf16(a, w8, acc[nt], 0, 0, 0);
        }
    }
#pragma unroll
    for (int nt = 0; nt < 4; ++nt) {
        int o = nt * 16 + row16;
        bf16x4 v;
        v[0] = (__bf16)acc[nt][0]; v[1] = (__bf16)acc[nt][1];
        v[2] = (__bf16)acc[nt][2]; v[3] = (__bf16)acc[nt][3];
        __bf16* dst = sftT + ((size_t)b * OUTF + o) * NTOK + mbase + g * 4;
        *(bf16x4*)dst = v;
    }
}

// ---------------- Kernel B: out = PReLU(adj @ seq_fts + bias) ----------------
// grid = 1024 (256 batches x 4 row-chunks of 128), block = 256 (4 waves).
// Wave w owns rows [w*32, w*32+32) of the chunk: stages its own stripe into a
// wave-private double-buffered LDS region (4 KB per buffer), consumes it, no
// cross-wave sharing -> zero __syncthreads. vmcnt(4) keeps next chunk's 4
// global_load_lds in flight across the compute phase.
__global__ __launch_bounds__(256, 4) void GCN_agg_kernel(
        const float* __restrict__ adj, const __bf16* __restrict__ sftT,
        const float* __restrict__ bias, const float* __restrict__ alpha_p,
        float* __restrict__ out) {
    __shared__ float lds[4][2][1024];   // [wave][buf][32 rows x 32 k] = 32 KB

    int blk  = blockIdx.x;
    int b    = blk >> 2;
    int m0   = (blk & 3) * 128;
    int tid  = threadIdx.x;
    int wave = tid >> 6;
    int lane = tid & 63;
    int row16 = lane & 15;
    int g     = lane >> 4;
    int wr    = wave * 32;

    // --- staging addresses (source pre-swizzled, LDS dest linear) ---
    // Each stage instr i writes 8 rows x 32 floats linearly: lane l -> LDS
    // float offset l*4 (row = l>>3, slot = l&7). We want LDS[row][s] to hold
    // global slot (s ^ (row&7)), so lane fetches slot (l&7) ^ (l>>3).
    int rloc = lane >> 3;               // 0..7 row within an 8-row group
    int slot = (lane & 7) ^ rloc;       // swizzled source 16B-slot
    const float* gsrc = adj + ((size_t)b * NTOK + m0 + wr + rloc) * NTOK + slot * 4;

    // B-frags straight from global (bf16, 16B/lane, L1/L2-resident panel)
    const __bf16* brow = sftT + ((size_t)b * OUTF + row16) * NTOK + g * 8;

    float* buf0 = &lds[wave][0][0];
    float* buf1 = &lds[wave][1][0];

#define STAGE(dst, kcc) do {                                                   \
    _Pragma("unroll")                                                          \
    for (int i_ = 0; i_ < 4; ++i_)                                             \
        __builtin_amdgcn_global_load_lds(                                      \
            (GChar*)(gsrc + (kcc) + (size_t)i_ * 8 * NTOK),                    \
            (LChar*)((dst) + i_ * 256), 16, 0, 0);                             \
} while (0)

    // swizzled ds_read offsets (floats); note (16+row16)&7 == row16&7
    int rs  = row16 & 7;
    int ps0 = ((g * 2 + 0) ^ rs) * 4;
    int ps1 = ((g * 2 + 1) ^ rs) * 4;
    int rd0 = row16 * 32;               // mt=0 row base
    int rd1 = (16 + row16) * 32;        // mt=1 row base

    f32x4 acc[2][4] = {};
    STAGE(buf0, 0);                      // prologue: chunk 0 -> buf0

#pragma unroll 1
    for (int it = 0; it < 15; ++it) {
        int kc = it * 32;
        const float* cur = (it & 1) ? buf1 : buf0;
        float*       nxt = (it & 1) ? buf0 : buf1;

        // (1) B-frag loads for this chunk (oldest-after-stage ordering matters)
        bf16x8 bb0 = *(const bf16x8*)(brow + kc);
        bf16x8 bb1 = *(const bf16x8*)(brow + (size_t)16 * NTOK + kc);
        bf16x8 bb2 = *(const bf16x8*)(brow + (size_t)32 * NTOK + kc);
        bf16x8 bb3 = *(const bf16x8*)(brow + (size_t)48 * NTOK + kc);
        __builtin_amdgcn_sched_barrier(0);
        // (2) prefetch next chunk into the other buffer
        STAGE(nxt, kc + 32);
        __builtin_amdgcn_sched_barrier(0);
        // (3) wait: drains stage_it + bb_it, leaves stage_{it+1} (4) in flight
        asm volatile("s_waitcnt vmcnt(4)" ::: "memory");
        __builtin_amdgcn_sched_barrier(0);

        // (4) ds_read A-frags (swizzled), cvt, 8 MFMAs
        float4 f00 = *(const float4*)(cur + rd0 + ps0);
        float4 f01 = *(const float4*)(cur + rd0 + ps1);
        float4 f10 = *(const float4*)(cur + rd1 + ps0);
        float4 f11 = *(const float4*)(cur + rd1 + ps1);
        bf16x8 a0 = pack8(f00, f01);
        bf16x8 a1 = pack8(f10, f11);
        acc[0][0] = __builtin_amdgcn_mfma_f32_16x16x32_bf16(a0, bb0, acc[0][0], 0, 0, 0);
        acc[1][0] = __builtin_amdgcn_mfma_f32_16x16x32_bf16(a1, bb0, acc[1][0], 0, 0, 0);
        acc[0][1] = __builtin_amdgcn_mfma_f32_16x16x32_bf16(a0, bb1, acc[0][1], 0, 0, 0);
        acc[1][1] = __builtin_amdgcn_mfma_f32_16x16x32_bf16(a1, bb1, acc[1][1], 0, 0, 0);
        acc[0][2] = __builtin_amdgcn_mfma_f32_16x16x32_bf16(a0, bb2, acc[0][2], 0, 0, 0);
        acc[1][2] = __builtin_amdgcn_mfma_f32_16x16x32_bf16(a1, bb2, acc[1][2], 0, 0, 0);
        acc[0][3] = __builtin_amdgcn_mfma_f32_16x16x32_bf16(a0, bb3, acc[0][3], 0, 0, 0);
        acc[1][3] = __builtin_amdgcn_mfma_f32_16x16x32_bf16(a1, bb3, acc[1][3], 0, 0, 0);
    }

    // ---- final chunk (kc = 480), buffer = buf1, nothing left to stage ----
    {
        int kc = 480;
        const float* cur = buf1;
        bf16x8 bb0 = *(const bf16x8*)(brow + kc);
        bf16x8 bb1 = *(const bf16x8*)(brow + (size_t)16 * NTOK + kc);
        bf16x8 bb2 = *(const bf16x8*)(brow + (size_t)32 * NTOK + kc);
        bf16x8 bb3 = *(const bf16x8*)(brow + (size_t)48 * NTOK + kc);
        asm volatile("s_waitcnt vmcnt(0)" ::: "memory");
        __builtin_amdgcn_sched_barrier(0);

        float4 f00 = *(const float4*)(cur + rd0 + ps0);
        float4 f01 = *(const float4*)(cur + rd0 + ps1);
        float4 f10 = *(const float4*)(cur + rd1 + ps0);
        float4 f11 = *(const float4*)(cur + rd1 + ps1);
        bf16x8 a0 = pack8(f00, f01);
        bf16x8 a1 = pack8(f10, f11);
        acc[0][0] = __builtin_amdgcn_mfma_f32_16x16x32_bf16(a0, bb0, acc[0][0], 0, 0, 0);
        acc[1][0] = __builtin_amdgcn_mfma_f32_16x16x32_bf16(a1, bb0, acc[1][0], 0, 0, 0);
        acc[0][1] = __builtin_amdgcn_mfma_f32_16x16x32_bf16(a0, bb1, acc[0][1], 0, 0, 0);
        acc[1][1] = __builtin_amdgcn_mfma_f32_16x16x32_bf16(a1, bb1, acc[1][1], 0, 0, 0);
        acc[0][2] = __builtin_amdgcn_mfma_f32_16x16x32_bf16(a0, bb2, acc[0][2], 0, 0, 0);
        acc[1][2] = __builtin_amdgcn_mfma_f32_16x16x32_bf16(a1, bb2, acc[1][2], 0, 0, 0);
        acc[0][3] = __builtin_amdgcn_mfma_f32_16x16x32_bf16(a0, bb3, acc[0][3], 0, 0, 0);
        acc[1][3] = __builtin_amdgcn_mfma_f32_16x16x32_bf16(a1, bb3, acc[1][3], 0, 0, 0);
    }
#undef STAGE

    // ---- epilogue: bias + PReLU + store (same as R1, verified) ----
    const float alpha = alpha_p[0];
#pragma unroll
    for (int mt = 0; mt < 2; ++mt) {
#pragma unroll
        for (int nt = 0; nt < 4; ++nt) {
            int o = nt * 16 + row16;
            float bv = bias[o];
            int m = m0 + wr + mt * 16 + g * 4;   // C/D row = g*4 + j
            float* op = out + ((size_t)b * NTOK + m) * OUTF + o;
#pragma unroll
            for (int j = 0; j < 4; ++j) {
                float v = acc[mt][nt][j] + bv;
                op[(size_t)j * OUTF] = (v >= 0.f) ? v : alpha * v;
            }
        }
    }
}

extern "C" void kernel_launch(void* const* d_in, const int* in_sizes, int n_in,
                              void* d_out, int out_size, void* d_ws, size_t ws_size,
                              hipStream_t stream) {
    const float* seq   = (const float*)d_in[0];
    const float* adj   = (const float*)d_in[1];
    const float* W     = (const float*)d_in[2];
    const float* bias  = (const float*)d_in[3];
    const float* alpha = (const float*)d_in[4];
    float* out = (float*)d_out;
    __bf16* sftT = (__bf16*)d_ws;   // 256*64*512*2 = 16 MB scratch

    GCN_fc_kernel<<<dim3(2048), dim3(256), 0, stream>>>(seq, W, sftT);
    GCN_agg_kernel<<<dim3(1024), dim3(256), 0, stream>>>(adj, sftT, bias, alpha, out);
}

// Round 4
// 93.315 us; speedup vs baseline: 1.1209x; 1.0568x over previous
//
#include <hip/hip_runtime.h>
#include <hip/hip_bf16.h>

// GCN forward: out = PReLU(adj @ (seq @ W^T) + bias)
// B=256, N=512, IN_FT=OUT_FT=64. Output fp32.
// Kernel A: seq_fts^T bf16 [b][o][tok] into d_ws (verified R1/R3).
// Kernel B v3: waves split OUT_FT; block of 4 waves shares one 32-row adj
//   panel staged in 512B-per-row chunks (DRAM-burst friendly) via
//   global_load_lds, double-buffered, counted vmcnt, XOR-swizzle, XCD swizzle.

#define BATCH 256
#define NTOK  512
#define INF   64
#define OUTF  64

typedef __attribute__((ext_vector_type(8))) __bf16 bf16x8;
typedef __attribute__((ext_vector_type(4))) __bf16 bf16x4;
typedef __attribute__((ext_vector_type(4))) float  f32x4;

typedef const __attribute__((address_space(1))) char GChar;
typedef __attribute__((address_space(3))) char LChar;

__device__ __forceinline__ bf16x8 load_cvt8(const float* __restrict__ p) {
    float4 lo = *(const float4*)p;
    float4 hi = *(const float4*)(p + 4);
    bf16x8 r;
    r[0] = (__bf16)lo.x; r[1] = (__bf16)lo.y; r[2] = (__bf16)lo.z; r[3] = (__bf16)lo.w;
    r[4] = (__bf16)hi.x; r[5] = (__bf16)hi.y; r[6] = (__bf16)hi.z; r[7] = (__bf16)hi.w;
    return r;
}

__device__ __forceinline__ bf16x8 pack8(float4 lo, float4 hi) {
    bf16x8 r;
    r[0] = (__bf16)lo.x; r[1] = (__bf16)lo.y; r[2] = (__bf16)lo.z; r[3] = (__bf16)lo.w;
    r[4] = (__bf16)hi.x; r[5] = (__bf16)hi.y; r[6] = (__bf16)hi.z; r[7] = (__bf16)hi.w;
    return r;
}

// ---------------- Kernel A: seq_fts^T = (seq @ W^T)^T -> bf16 ----------------
__global__ __launch_bounds__(256) void GCN_fc_kernel(
        const float* __restrict__ seq, const float* __restrict__ W,
        __bf16* __restrict__ sftT) {
    int blk  = blockIdx.x;
    int b    = blk >> 3;
    int m0   = (blk & 7) * 64;
    int tid  = threadIdx.x;
    int wave = tid >> 6;
    int lane = tid & 63;
    int row16 = lane & 15;
    int g     = lane >> 4;
    int mbase = m0 + wave * 16;

    const float* sp = seq + ((size_t)b * NTOK + (mbase + row16)) * INF + g * 8;
    const float* wp = W + (size_t)row16 * INF + g * 8;

    f32x4 acc[4] = {};
#pragma unroll
    for (int ks = 0; ks < 2; ++ks) {
        bf16x8 a = load_cvt8(sp + ks * 32);
#pragma unroll
        for (int nt = 0; nt < 4; ++nt) {
            bf16x8 w8 = load_cvt8(wp + (size_t)nt * 16 * INF + ks * 32);
            acc[nt] = __builtin_amdgcn_mfma_f32_16x16x32_bf16(a, w8, acc[nt], 0, 0, 0);
        }
    }
#pragma unroll
    for (int nt = 0; nt < 4; ++nt) {
        int o = nt * 16 + row16;
        bf16x4 v;
        v[0] = (__bf16)acc[nt][0]; v[1] = (__bf16)acc[nt][1];
        v[2] = (__bf16)acc[nt][2]; v[3] = (__bf16)acc[nt][3];
        __bf16* dst = sftT + ((size_t)b * OUTF + o) * NTOK + mbase + g * 4;
        *(bf16x4*)dst = v;
    }
}

// ---------------- Kernel B: out = PReLU(adj @ seq_fts + bias) ----------------
// grid = 4096 (256 batches x 16 row-groups of 32), block = 256 (4 waves).
// Waves split OUT_FT (16 each); block shares a [32 x 128] fp32 adj chunk in
// LDS (512 B contiguous per row -> DRAM-burst friendly). Double-buffered,
// stage via global_load_lds; counted vmcnt keeps the next chunk in flight
// across both barriers. XOR swizzle (slot ^= row&7) on source + ds_read.
__global__ __launch_bounds__(256, 5) void GCN_agg_kernel(
        const float* __restrict__ adj, const __bf16* __restrict__ sftT,
        const float* __restrict__ bias, const float* __restrict__ alpha_p,
        float* __restrict__ out) {
    __shared__ float lds[2][4096];   // 2 x [32 rows x 128 floats] = 32 KB

    // XCD-chunk swizzle: the 16 row-group blocks of one batch land on one XCD
    int p = blockIdx.x;
    int logical = (p & 7) * 512 + (p >> 3);   // 4096 % 8 == 0 -> bijective
    int b  = logical >> 4;
    int m0 = (logical & 15) * 32;

    int tid  = threadIdx.x;
    int wave = tid >> 6;
    int lane = tid & 63;
    int row16 = lane & 15;
    int g     = lane >> 4;
    int half  = lane >> 5;           // 0/1: which row of the 2-row load
    int l31   = lane & 31;           // 16B slot position within the 512B row

    const float* gbase = adj + ((size_t)b * NTOK + m0) * NTOK;
    // B-frags from global: sftT[b][wave*16+row16][k], 16B/lane
    const __bf16* brow = sftT + ((size_t)b * OUTF + wave * 16 + row16) * NTOK + g * 8;

    // STAGE one [32 x 128] chunk: 16 x global_load_lds (1 KB each), 4 per wave.
    // Load j_ covers rows (2*(wave*4+j_), +1); lane fetches swizzled slot
    // (l31 ^ (rloc&7)) so linear LDS holds LDS[row][s] = global[row][s^(row&7)].
#define STAGE(dst, kcc) do {                                                   \
    _Pragma("unroll")                                                          \
    for (int j_ = 0; j_ < 4; ++j_) {                                           \
        int idx_  = wave * 4 + j_;                                             \
        int rloc_ = 2 * idx_ + half;                                           \
        int slot_ = l31 ^ ((2 * j_ + half) & 7);                               \
        __builtin_amdgcn_global_load_lds(                                      \
            (GChar*)(gbase + (size_t)rloc_ * NTOK + (kcc) + slot_ * 4),        \
            (LChar*)((dst) + idx_ * 256), 16, 0, 0);                           \
    }                                                                          \
} while (0)

    int rs = row16 & 7;              // (16+row16)&7 == row16&7

    f32x4 acc[2] = {};
    STAGE(&lds[0][0], 0);            // prologue: chunk 0 -> buf0

#pragma unroll
    for (int it = 0; it < 4; ++it) {
        int kc = it * 128;
        float* cur = &lds[it & 1][0];
        float* nxt = &lds[(it + 1) & 1][0];

        // (1) B-frag loads for this chunk (BEFORE stage so final vmcnt can
        //     drain them while leaving the stage in flight)
        bf16x8 bb0 = *(const bf16x8*)(brow + kc);
        bf16x8 bb1 = *(const bf16x8*)(brow + kc + 32);
        bf16x8 bb2 = *(const bf16x8*)(brow + kc + 64);
        bf16x8 bb3 = *(const bf16x8*)(brow + kc + 96);

        // (2) top barrier (it>0): everyone done reading the buffer we are
        //     about to overwrite
        if (it > 0) {
            __builtin_amdgcn_sched_barrier(0);
            __builtin_amdgcn_s_barrier();
            __builtin_amdgcn_sched_barrier(0);
        }
        // (3) prefetch next chunk
        if (it < 3) STAGE(nxt, kc + 128);
        __builtin_amdgcn_sched_barrier(0);

        // (4) drain stage_cur (leave bb + stage_nxt in flight), then barrier
        if (it < 3) asm volatile("s_waitcnt vmcnt(8)" ::: "memory");
        else        asm volatile("s_waitcnt vmcnt(4)" ::: "memory");
        __builtin_amdgcn_sched_barrier(0);
        __builtin_amdgcn_s_barrier();
        __builtin_amdgcn_sched_barrier(0);
        // (5) drain bb (leave stage_nxt in flight)
        if (it < 3) asm volatile("s_waitcnt vmcnt(4)" ::: "memory");
        else        asm volatile("s_waitcnt vmcnt(0)" ::: "memory");
        __builtin_amdgcn_sched_barrier(0);

        // (6) ds_read A-frags (swizzled) + 8 MFMAs
#pragma unroll
        for (int ks = 0; ks < 4; ++ks) {
            int s0  = ks * 8 + g * 2;
            int sl0 = (s0 ^ rs) * 4;
            int sl1 = ((s0 ^ rs) ^ 1) * 4;   // (s0+1)^rs, s0 even
            float4 f00 = *(const float4*)(cur + row16 * 128 + sl0);
            float4 f01 = *(const float4*)(cur + row16 * 128 + sl1);
            float4 f10 = *(const float4*)(cur + (16 + row16) * 128 + sl0);
            float4 f11 = *(const float4*)(cur + (16 + row16) * 128 + sl1);
            bf16x8 a0 = pack8(f00, f01);
            bf16x8 a1 = pack8(f10, f11);
            bf16x8 bb = (ks == 0) ? bb0 : (ks == 1) ? bb1 : (ks == 2) ? bb2 : bb3;
            acc[0] = __builtin_amdgcn_mfma_f32_16x16x32_bf16(a0, bb, acc[0], 0, 0, 0);
            acc[1] = __builtin_amdgcn_mfma_f32_16x16x32_bf16(a1, bb, acc[1], 0, 0, 0);
        }
    }
#undef STAGE

    // ---- epilogue: bias + PReLU + store ----
    const float alpha = alpha_p[0];
    int o = wave * 16 + row16;
    float bv = bias[o];
#pragma unroll
    for (int mt = 0; mt < 2; ++mt) {
        int m = m0 + mt * 16 + g * 4;        // C/D row = g*4 + j
        float* op = out + ((size_t)b * NTOK + m) * OUTF + o;
#pragma unroll
        for (int j = 0; j < 4; ++j) {
            float v = acc[mt][j] + bv;
            op[(size_t)j * OUTF] = (v >= 0.f) ? v : alpha * v;
        }
    }
}

extern "C" void kernel_launch(void* const* d_in, const int* in_sizes, int n_in,
                              void* d_out, int out_size, void* d_ws, size_t ws_size,
                              hipStream_t stream) {
    const float* seq   = (const float*)d_in[0];
    const float* adj   = (const float*)d_in[1];
    const float* W     = (const float*)d_in[2];
    const float* bias  = (const float*)d_in[3];
    const float* alpha = (const float*)d_in[4];
    float* out = (float*)d_out;
    __bf16* sftT = (__bf16*)d_ws;   // 256*64*512*2 = 16 MB scratch

    GCN_fc_kernel<<<dim3(2048), dim3(256), 0, stream>>>(seq, W, sftT);
    GCN_agg_kernel<<<dim3(4096), dim3(256), 0, stream>>>(adj, sftT, bias, alpha, out);
}

// Round 5
// 76.187 us; speedup vs baseline: 1.3728x; 1.2248x over previous
//
#include <hip/hip_runtime.h>
#include <hip/hip_bf16.h>

// GCN forward, FUSED single kernel: out = PReLU(adj @ (seq @ W^T) + bias)
// B=256, N=512, IN_FT=OUT_FT=64. Output fp32.
// grid = 256 (1 block = 1 batch = 1 CU, no tail), block = 1024 (16 waves).
// Phase 1: seq_fts = seq@W^T via MFMA -> swizzled bf16 LDS [64 o][512 k].
// Redistribute: each wave loads its 16-col B-frags for all K into 64 VGPRs.
// Phase 2: stream adj (1 MB/batch) through 4 row-group double-buffered LDS
//   chunks [128 rows x 32 k] fp32 via global_load_lds, counted vmcnt(4),
//   XOR-swizzled source+read; 8 MFMAs per wave per chunk; bias in acc init.

#define BATCH 256
#define NTOK  512
#define INF   64
#define OUTF  64

typedef __attribute__((ext_vector_type(8))) __bf16 bf16x8;
typedef __attribute__((ext_vector_type(4))) __bf16 bf16x4;
typedef __attribute__((ext_vector_type(4))) float  f32x4;

typedef const __attribute__((address_space(1))) char GChar;
typedef __attribute__((address_space(3))) char LChar;

__device__ __forceinline__ bf16x8 load_cvt8(const float* __restrict__ p) {
    float4 lo = *(const float4*)p;
    float4 hi = *(const float4*)(p + 4);
    bf16x8 r;
    r[0] = (__bf16)lo.x; r[1] = (__bf16)lo.y; r[2] = (__bf16)lo.z; r[3] = (__bf16)lo.w;
    r[4] = (__bf16)hi.x; r[5] = (__bf16)hi.y; r[6] = (__bf16)hi.z; r[7] = (__bf16)hi.w;
    return r;
}

__device__ __forceinline__ bf16x8 pack8(float4 lo, float4 hi) {
    bf16x8 r;
    r[0] = (__bf16)lo.x; r[1] = (__bf16)lo.y; r[2] = (__bf16)lo.z; r[3] = (__bf16)lo.w;
    r[4] = (__bf16)hi.x; r[5] = (__bf16)hi.y; r[6] = (__bf16)hi.z; r[7] = (__bf16)hi.w;
    return r;
}

__global__ __launch_bounds__(1024, 4) void GCN_fused_kernel(
        const float* __restrict__ seq, const float* __restrict__ adj,
        const float* __restrict__ W, const float* __restrict__ bias,
        const float* __restrict__ alpha_p, float* __restrict__ out) {
    __shared__ float smem[32768];            // 128 KB, phase-overlaid

    int b    = blockIdx.x;
    int tid  = threadIdx.x;
    int wave = tid >> 6;                     // 0..15
    int lane = tid & 63;
    int row16 = lane & 15;
    int g     = lane >> 4;                   // 0..3
    int c     = wave & 3;                    // col-group: o in [c*16, c*16+16)
    int r     = wave >> 2;                   // row-group: m in [r*128, r*128+128)
    int rs    = row16 & 7;

    __bf16* sft = (__bf16*)smem;             // [64 o][512 k] bf16, slot-swizzled

    // ================= Phase 1: sft[o][k] = sum_f seq[b][k][f] * W[o][f] ====
    // Wave handles tokens [wave*32, wave*32+32), all 64 o.
    {
        int mb = wave * 32;
        bf16x8 wf[4][2];
#pragma unroll
        for (int nt = 0; nt < 4; ++nt)
#pragma unroll
            for (int ks = 0; ks < 2; ++ks)
                wf[nt][ks] = load_cvt8(W + (size_t)(nt * 16 + row16) * INF + ks * 32 + g * 8);

#pragma unroll
        for (int mt = 0; mt < 2; ++mt) {
            f32x4 pa[4] = {};
#pragma unroll
            for (int ks = 0; ks < 2; ++ks) {
                bf16x8 af = load_cvt8(seq + ((size_t)b * NTOK + mb + mt * 16 + row16) * INF + ks * 32 + g * 8);
#pragma unroll
                for (int nt = 0; nt < 4; ++nt)
                    pa[nt] = __builtin_amdgcn_mfma_f32_16x16x32_bf16(af, wf[nt][ks], pa[nt], 0, 0, 0);
            }
            // D: col(o) = row16-part, row(tok) = g*4 + reg. Store swizzled:
            // slot s = k>>3 stored at s^(o&7); within-slot offset (k&7).
#pragma unroll
            for (int nt = 0; nt < 4; ++nt) {
                int o    = nt * 16 + row16;
                int ktok = mb + mt * 16 + g * 4;
                int sw   = (ktok >> 3) ^ (o & 7);
                bf16x4 v;
                v[0] = (__bf16)pa[nt][0]; v[1] = (__bf16)pa[nt][1];
                v[2] = (__bf16)pa[nt][2]; v[3] = (__bf16)pa[nt][3];
                *(bf16x4*)((char*)sft + (size_t)o * 1024 + sw * 16 + (ktok & 7) * 2) = v;
            }
        }
    }
    __syncthreads();

    // ============ Redistribute: B-frags for this wave's 16 cols, all K ======
    // bbr[t] = sft[t*32 + g*8 + j][orow], j=0..7  (slot t*4+g, swizzled)
    int orow = c * 16 + row16;
    bf16x8 bbr[16];
#pragma unroll
    for (int t = 0; t < 16; ++t) {
        int sw = ((t << 2) + g) ^ rs;
        bbr[t] = *(const bf16x8*)((const char*)sft + (size_t)orow * 1024 + sw * 16);
    }
    __syncthreads();

    // ================= Phase 2: out = PReLU(adj @ sft + bias) ===============
    float bv     = bias[orow];
    float alphav = alpha_p[0];
    f32x4 acc[8];
#pragma unroll
    for (int mt = 0; mt < 8; ++mt) { acc[mt][0] = bv; acc[mt][1] = bv; acc[mt][2] = bv; acc[mt][3] = bv; }

    // Drain ALL prior vmem (seq/W/bias/alpha) so loop vmcnt counts only stages
    asm volatile("s_waitcnt vmcnt(0)" ::: "memory");
    __builtin_amdgcn_sched_barrier(0);

    // Staging: group r, chunk [128 rows x 32 k] fp32 = 16 KB, 16 loads (4/wave).
    // Lane l of load idx_: row = idx_*8 + (l>>3), fetches swizzled slot
    // (l&7)^(l>>3) so linear LDS holds LDS[row][s] = global[row][s^(row&7)].
    int rl = lane >> 3;
    int sl = (lane & 7) ^ rl;
    const float* gsrc = adj + ((size_t)b * NTOK + r * 128 + rl) * NTOK + sl * 4;
    float* gb0 = smem + (size_t)(r * 2 + 0) * 4096;
    float* gb1 = smem + (size_t)(r * 2 + 1) * 4096;

#define STAGE(dstf, kcc) do {                                                  \
    _Pragma("unroll")                                                          \
    for (int i_ = 0; i_ < 4; ++i_) {                                           \
        int idx_ = c * 4 + i_;                                                 \
        __builtin_amdgcn_global_load_lds(                                      \
            (GChar*)(gsrc + (size_t)idx_ * 8 * NTOK + (kcc)),                  \
            (LChar*)((dstf) + idx_ * 256), 16, 0, 0);                          \
    }                                                                          \
} while (0)

    STAGE(gb0, 0);                           // prologue: chunk 0

#pragma unroll
    for (int it = 0; it < 16; ++it) {
        int kc = it * 32;
        float* cur = (it & 1) ? gb1 : gb0;
        float* nxt = (it & 1) ? gb0 : gb1;

        if (it > 0) {                        // all waves done reading nxt's old data
            __builtin_amdgcn_sched_barrier(0);
            __builtin_amdgcn_s_barrier();
            __builtin_amdgcn_sched_barrier(0);
        }
        if (it < 15) STAGE(nxt, kc + 32);
        __builtin_amdgcn_sched_barrier(0);
        if (it < 15) asm volatile("s_waitcnt vmcnt(4)" ::: "memory");  // drain cur, keep nxt
        else         asm volatile("s_waitcnt vmcnt(0)" ::: "memory");
        __builtin_amdgcn_sched_barrier(0);
        __builtin_amdgcn_s_barrier();        // cur landed for ALL staging waves
        __builtin_amdgcn_sched_barrier(0);

        // compute: 8 m-tiles x (2 swizzled ds_read_b128 -> pack -> MFMA)
#pragma unroll
        for (int mt = 0; mt < 8; ++mt) {
            int rloc = mt * 16 + row16;
            int s0   = (g * 2) ^ rs;
            float4 f0 = *(const float4*)(cur + rloc * 32 + s0 * 4);
            float4 f1 = *(const float4*)(cur + rloc * 32 + (s0 ^ 1) * 4);
            bf16x8 a = pack8(f0, f1);
            acc[mt] = __builtin_amdgcn_mfma_f32_16x16x32_bf16(a, bbr[it], acc[mt], 0, 0, 0);
        }
    }
#undef STAGE

    // ================= Epilogue: PReLU + store (bias already in acc) ========
#pragma unroll
    for (int mt = 0; mt < 8; ++mt) {
        int m = r * 128 + mt * 16 + g * 4;   // C/D row = g*4 + j
        float* op = out + ((size_t)b * NTOK + m) * OUTF + orow;
#pragma unroll
        for (int j = 0; j < 4; ++j) {
            float v = acc[mt][j];
            op[(size_t)j * OUTF] = (v >= 0.f) ? v : alphav * v;
        }
    }
}

extern "C" void kernel_launch(void* const* d_in, const int* in_sizes, int n_in,
                              void* d_out, int out_size, void* d_ws, size_t ws_size,
                              hipStream_t stream) {
    const float* seq   = (const float*)d_in[0];
    const float* adj   = (const float*)d_in[1];
    const float* W     = (const float*)d_in[2];
    const float* bias  = (const float*)d_in[3];
    const float* alpha = (const float*)d_in[4];
    float* out = (float*)d_out;

    GCN_fused_kernel<<<dim3(BATCH), dim3(1024), 0, stream>>>(seq, adj, W, bias, alpha, out);
}

// Round 6
// 72.089 us; speedup vs baseline: 1.4509x; 1.0569x over previous
//
#include <hip/hip_runtime.h>
#include <hip/hip_bf16.h>

// GCN forward, FUSED single kernel v2: out = PReLU(adj @ (seq @ W^T) + bias)
// B=256, N=512, IN_FT=OUT_FT=64. Output fp32.
// grid = 256 (1 block = 1 batch = 1 CU), block = 512 (8 waves), LDS 128 KB.
// Phase 2 chunks are [32 rows x FULL K=512] fp32 (64 KB, double-buffered):
// each adj row is ONE contiguous 2-KB visit -> 16x fewer DRAM activations
// than the [128x32] layout (theory: R5 was activation-rate-bound).
// Chunk 0 is staged before phase 1 so its latency hides under fc compute.

#define BATCH 256
#define NTOK  512
#define INF   64
#define OUTF  64

typedef __attribute__((ext_vector_type(8))) __bf16 bf16x8;
typedef __attribute__((ext_vector_type(4))) __bf16 bf16x4;
typedef __attribute__((ext_vector_type(4))) float  f32x4;

typedef const __attribute__((address_space(1))) char GChar;
typedef __attribute__((address_space(3))) char LChar;

__device__ __forceinline__ bf16x8 load_cvt8(const float* __restrict__ p) {
    float4 lo = *(const float4*)p;
    float4 hi = *(const float4*)(p + 4);
    bf16x8 r;
    r[0] = (__bf16)lo.x; r[1] = (__bf16)lo.y; r[2] = (__bf16)lo.z; r[3] = (__bf16)lo.w;
    r[4] = (__bf16)hi.x; r[5] = (__bf16)hi.y; r[6] = (__bf16)hi.z; r[7] = (__bf16)hi.w;
    return r;
}

__device__ __forceinline__ bf16x8 pack8(float4 lo, float4 hi) {
    bf16x8 r;
    r[0] = (__bf16)lo.x; r[1] = (__bf16)lo.y; r[2] = (__bf16)lo.z; r[3] = (__bf16)lo.w;
    r[4] = (__bf16)hi.x; r[5] = (__bf16)hi.y; r[6] = (__bf16)hi.z; r[7] = (__bf16)hi.w;
    return r;
}

__global__ __launch_bounds__(512, 2) void GCN_fused_kernel(
        const float* __restrict__ seq, const float* __restrict__ adj,
        const float* __restrict__ W, const float* __restrict__ bias,
        const float* __restrict__ alpha_p, float* __restrict__ out) {
    __shared__ float smem[32768];            // 128 KB

    int b    = blockIdx.x;
    int tid  = threadIdx.x;
    int wave = tid >> 6;                     // 0..7
    int lane = tid & 63;
    int row16 = lane & 15;
    int g     = lane >> 4;                   // 0..3
    int c     = wave & 3;                    // col-group: o in [c*16, c*16+16)
    int mt    = wave >> 2;                   // 0/1: rows [mt*16, mt*16+16) of chunk
    int rs    = row16 & 7;

    __bf16* sft = (__bf16*)smem;             // [64 o][512 k] bf16, slot-swizzled (lower 64 KB)
    float* buf0 = smem + 16384;              // upper 64 KB  (even chunks)
    float* buf1 = smem;                      // lower 64 KB, overlays sft (odd chunks)

    // --- adj staging addresses: chunk = [32 rows x 512 k] fp32 = 64 KB ---
    // 64 loads of 1 KB (64 lanes x 16 B), 8 per wave: idx = wave*8+i,
    // row = idx>>1, half = idx&1. Row is WAVE-UNIFORM per load, so the XOR
    // swizzle permutes 16-B slots within the same row's 1-KB half:
    // LDS[row][s] = G[row][half*64 + ((s&63) ^ (row&7))].
    const float* gadj = adj + (size_t)b * NTOK * NTOK;

#define STAGE(dstf, rbase) do {                                                \
    _Pragma("unroll")                                                          \
    for (int i_ = 0; i_ < 8; ++i_) {                                           \
        int idx_  = wave * 8 + i_;                                             \
        int row_  = idx_ >> 1;                                                 \
        int half_ = idx_ & 1;                                                  \
        __builtin_amdgcn_global_load_lds(                                      \
            (GChar*)(gadj + (size_t)((rbase) + row_) * NTOK + half_ * 256      \
                     + (lane ^ (row_ & 7)) * 4),                               \
            (LChar*)((dstf) + idx_ * 256), 16, 0, 0);                          \
    }                                                                          \
} while (0)

    STAGE(buf0, 0);                          // chunk 0 in flight during phase 1

    // ================= Phase 1: sft[o][k] = (seq @ W^T)^T ===================
    // Wave handles tokens [wave*64, wave*64+64), all 64 o.
    {
        int mb = wave * 64;
        bf16x8 wf[4][2];
#pragma unroll
        for (int nt = 0; nt < 4; ++nt)
#pragma unroll
            for (int ks = 0; ks < 2; ++ks)
                wf[nt][ks] = load_cvt8(W + (size_t)(nt * 16 + row16) * INF + ks * 32 + g * 8);

#pragma unroll
        for (int mt2 = 0; mt2 < 4; ++mt2) {
            f32x4 pa[4] = {};
#pragma unroll
            for (int ks = 0; ks < 2; ++ks) {
                bf16x8 af = load_cvt8(seq + ((size_t)b * NTOK + mb + mt2 * 16 + row16) * INF + ks * 32 + g * 8);
#pragma unroll
                for (int nt = 0; nt < 4; ++nt)
                    pa[nt] = __builtin_amdgcn_mfma_f32_16x16x32_bf16(af, wf[nt][ks], pa[nt], 0, 0, 0);
            }
            // D: col(o)=row16-part, row(tok)=g*4+reg. Swizzled store:
            // 16-B slot s = k>>3 stored at s ^ (o&7), within-slot offset k&7.
#pragma unroll
            for (int nt = 0; nt < 4; ++nt) {
                int o    = nt * 16 + row16;
                int ktok = mb + mt2 * 16 + g * 4;
                int sw   = (ktok >> 3) ^ (o & 7);
                bf16x4 v;
                v[0] = (__bf16)pa[nt][0]; v[1] = (__bf16)pa[nt][1];
                v[2] = (__bf16)pa[nt][2]; v[3] = (__bf16)pa[nt][3];
                *(bf16x4*)((char*)sft + (size_t)o * 1024 + sw * 16 + (ktok & 7) * 2) = v;
            }
        }
    }
    // bias/alpha now so they're drained by the syncthreads below
    int orow     = c * 16 + row16;
    float bv     = bias[orow];
    float alphav = alpha_p[0];
    __syncthreads();

    // ============ Redistribute: B-frags, this wave's 16 cols, all K =========
    // bbr[t] = sft[t*32 + g*8 + j][orow]  (slot t*4+g, swizzled by orow&7==rs)
    bf16x8 bbr[16];
#pragma unroll
    for (int t = 0; t < 16; ++t) {
        int sw = ((t << 2) + g) ^ rs;
        bbr[t] = *(const bf16x8*)((const char*)sft + (size_t)orow * 1024 + sw * 16);
    }
    __syncthreads();   // also drains all prior vmem incl. chunk-0 stage

    // ================= Phase 2: 16 chunks of [32 rows x 512 k] ==============
#pragma unroll 1
    for (int it = 0; it < 16; ++it) {
        float* cur = (it & 1) ? buf1 : buf0;
        float* nxt = (it & 1) ? buf0 : buf1;

        if (it > 0) {                        // all waves done reading nxt's old chunk
            __builtin_amdgcn_sched_barrier(0);
            __builtin_amdgcn_s_barrier();
            __builtin_amdgcn_sched_barrier(0);
        }
        if (it < 15) STAGE(nxt, (it + 1) * 32);
        __builtin_amdgcn_sched_barrier(0);
        // drain THIS chunk's 8 loads; keep next stage (8) + prior stores (4)
        if (it == 0)       asm volatile("s_waitcnt vmcnt(8)"  ::: "memory");
        else if (it < 15)  asm volatile("s_waitcnt vmcnt(12)" ::: "memory");
        else               asm volatile("s_waitcnt vmcnt(4)"  ::: "memory");
        __builtin_amdgcn_sched_barrier(0);
        __builtin_amdgcn_s_barrier();        // chunk landed for ALL waves
        __builtin_amdgcn_sched_barrier(0);

        // compute: rows [mt*16, +16), cols orow, full K. 16 MFMAs.
        f32x4 acc;
        acc[0] = bv; acc[1] = bv; acc[2] = bv; acc[3] = bv;
        int rowb = (mt * 16 + row16) * 512;
#pragma unroll
        for (int ks = 0; ks < 16; ++ks) {
            int s0 = (ks * 8 + g * 2) ^ rs;  // ks*8+g*2 even -> +1 slot is ^1
            float4 f0 = *(const float4*)(cur + rowb + s0 * 4);
            float4 f1 = *(const float4*)(cur + rowb + (s0 ^ 1) * 4);
            bf16x8 a = pack8(f0, f1);
            acc = __builtin_amdgcn_mfma_f32_16x16x32_bf16(a, bbr[ks], acc, 0, 0, 0);
        }

        // epilogue for this chunk: PReLU + store (bias pre-loaded in acc)
        int m = it * 32 + mt * 16 + g * 4;   // C/D row = g*4 + j
        float* op = out + ((size_t)b * NTOK + m) * OUTF + orow;
#pragma unroll
        for (int j = 0; j < 4; ++j) {
            float v = acc[j];
            op[(size_t)j * OUTF] = (v >= 0.f) ? v : alphav * v;
        }
    }
#undef STAGE
}

extern "C" void kernel_launch(void* const* d_in, const int* in_sizes, int n_in,
                              void* d_out, int out_size, void* d_ws, size_t ws_size,
                              hipStream_t stream) {
    const float* seq   = (const float*)d_in[0];
    const float* adj   = (const float*)d_in[1];
    const float* W     = (const float*)d_in[2];
    const float* bias  = (const float*)d_in[3];
    const float* alpha = (const float*)d_in[4];
    float* out = (float*)d_out;

    GCN_fused_kernel<<<dim3(BATCH), dim3(512), 0, stream>>>(seq, adj, W, bias, alpha, out);
}